// Round 2
// baseline (150.592 us; speedup 1.0000x reference)
//
#include <hip/hip_runtime.h>

#define N 8192
#define D 128
// (1/0.07) * log2(e): fold temperature AND base-2 conversion into A-side scale
#define SCALE_A 20.6098592f
#define NBX 64
#define NBY 8
#define NBLK (NBX * NBY)
#define FLAG_MAGIC 0x5CA1AB1Eu

using short8  = __attribute__((ext_vector_type(8))) short;
using float4v = __attribute__((ext_vector_type(4))) float;

#if __has_builtin(__builtin_amdgcn_exp2f)
#define EXP2(x) __builtin_amdgcn_exp2f(x)
#else
#define EXP2(x) __expf((x) * 0.69314718f)
#endif

// float -> bf16 (RNE) as raw ushort — identical bit behavior to the old prep.
static __device__ inline unsigned int f2bf(float f) {
    union { float f; unsigned int u; } x;
    x.f = f;
    unsigned int u = x.u;
    return (u + 0x7FFFu + ((u >> 16) & 1u)) >> 16;
}

// Issue the 16 fp32 float4 loads for one 128x128 B-tile (per-thread slice).
// Thread owns chunk column tc8 (16 bf16 -> 32B fp32) of rows trow + ch*16.
static __device__ __forceinline__ void issue_tile(
    const float4v* __restrict__ emb4, int cbase, int trow, int tc8,
    float4v (&r)[16])
{
    #pragma unroll
    for (int ch = 0; ch < 8; ++ch) {
        const size_t o = (size_t)(cbase + trow + ch * 16) * 32 + tc8 * 2;
        r[2 * ch]     = emb4[o];
        r[2 * ch + 1] = emb4[o + 1];
    }
}

// fp32 regs -> bf16 (RNE) -> swizzled LDS image, identical to the old prep+DMA
// image: slot(row,chunk) = row*16 + (chunk ^ (row&15)). With row = trow+ch*16,
// (row&15)==trow, so dst = base + ch*256 with base = trow*16 + (tc8^trow).
static __device__ __forceinline__ void convert_write(
    const float4v (&r)[16], uint4* dst)
{
    #pragma unroll
    for (int ch = 0; ch < 8; ++ch) {
        const float4v f0 = r[2 * ch], f1 = r[2 * ch + 1];
        uint4 w;
        w.x = f2bf(f0[0]) | (f2bf(f0[1]) << 16);
        w.y = f2bf(f0[2]) | (f2bf(f0[3]) << 16);
        w.z = f2bf(f1[0]) | (f2bf(f1[1]) << 16);
        w.w = f2bf(f1[2]) | (f2bf(f1[3]) << 16);
        dst[ch * 256] = w;
    }
}

// ONE kernel, ONE dispatch. Each block: 128 rows x 1024 cols, converting its
// own operands from fp32 emb (no cross-block data -> no coherence hazard, no
// init kernel). Partials are single-writer agent-scope stores; per-block MAGIC
// flags (poison-safe) gate a finalize done by block 0 only — all other blocks
// exit immediately, so no co-residency assumption exists anywhere.
__global__ __launch_bounds__(256, 2) void cl_fused(
    const float* __restrict__ emb, const int* __restrict__ labels,
    float* __restrict__ part, unsigned int* __restrict__ flags,
    float* __restrict__ out)
{
    __shared__ uint4 ldsB[128 * 16];   // 32KB single buffer (write/read phases split)
    __shared__ int   s_collab[1024];
    __shared__ float sred[2][4];

    const int tid  = threadIdx.x;
    const int lane = tid & 63;
    const int wave = tid >> 6;
    const int q    = lane >> 4;   // quad id 0..3
    const int c    = lane & 15;
    const int rw     = blockIdx.x * 128 + wave * 32;
    const int cbase0 = blockIdx.y * 1024;
    const int bid    = blockIdx.y * NBX + blockIdx.x;
    const int trow   = tid >> 4;  // 0..15
    const int tc8    = tid & 15;  // chunk id
    const float4v* emb4 = (const float4v*)emb;

    float4v r[16];
    issue_tile(emb4, cbase0, trow, tc8, r);      // tile 0 in flight

    // ---- A fragments: fp32 -> scaled bf16, once per block (dup cost ~0) ----
    short8 afrag[2][4];
    int rowlab[2][4];
    #pragma unroll
    for (int tr = 0; tr < 2; ++tr) {
        const int arow = rw + tr * 16 + c;
        #pragma unroll
        for (int ks = 0; ks < 4; ++ks) {
            const float4v a0 = emb4[(size_t)arow * 32 + ks * 8 + q * 2];
            const float4v a1 = emb4[(size_t)arow * 32 + ks * 8 + q * 2 + 1];
            union { short8 s; uint4 u; } w;
            w.u.x = f2bf(a0[0] * SCALE_A) | (f2bf(a0[1] * SCALE_A) << 16);
            w.u.y = f2bf(a0[2] * SCALE_A) | (f2bf(a0[3] * SCALE_A) << 16);
            w.u.z = f2bf(a1[0] * SCALE_A) | (f2bf(a1[1] * SCALE_A) << 16);
            w.u.w = f2bf(a1[2] * SCALE_A) | (f2bf(a1[3] * SCALE_A) << 16);
            afrag[tr][ks] = w.s;
        }
        #pragma unroll
        for (int reg = 0; reg < 4; ++reg)
            rowlab[tr][reg] = labels[rw + tr * 16 + q * 4 + reg];
    }

    // ---- column labels -> LDS once ----
    {
        int4 lv = *(const int4*)(labels + cbase0 + tid * 4);
        *(int4*)(&s_collab[tid * 4]) = lv;
    }

    // convert tile 0, prefetch tile 1 (fp32 regs fly under next MFMA phase)
    uint4* dst = &ldsB[trow * 16 + (tc8 ^ trow)];
    convert_write(r, dst);                       // compiler waits r's vmcnt here
    issue_tile(emb4, cbase0 + 128, trow, tc8, r);
    asm volatile("s_waitcnt lgkmcnt(0)" ::: "memory");   // own ds_writes done
    __builtin_amdgcn_s_barrier();
    __builtin_amdgcn_sched_barrier(0);

    float tot_a[2][4] = {{0.f,0.f,0.f,0.f},{0.f,0.f,0.f,0.f}};
    float pos_a[2][4] = {{0.f,0.f,0.f,0.f},{0.f,0.f,0.f,0.f}};

    #pragma unroll 1
    for (int it = 0; it < 8; ++it) {
        int collab[8];
        #pragma unroll
        for (int tc = 0; tc < 8; ++tc) collab[tc] = s_collab[it * 128 + tc * 16 + c];

        // ---- MFMA: 2 tile-rows x 8 tile-cols, K=128 in 4 steps ----
        float4v acc[2][8];
        #pragma unroll
        for (int tr = 0; tr < 2; ++tr)
            #pragma unroll
            for (int tc = 0; tc < 8; ++tc) {
                float4v z = {0.f, 0.f, 0.f, 0.f};
                acc[tr][tc] = z;
            }

        const short8* ldsS = (const short8*)ldsB;
        #pragma unroll
        for (int ks = 0; ks < 4; ++ks) {
            const short8* pk = ldsS + c * 16 + ((ks * 4 + q) ^ c);
            #pragma unroll
            for (int tc = 0; tc < 8; ++tc) {
                short8 b = pk[tc * 256];
                #pragma unroll
                for (int tr = 0; tr < 2; ++tr)
                    acc[tr][tc] = __builtin_amdgcn_mfma_f32_16x16x32_bf16(
                        afrag[tr][ks], b, acc[tr][tc], 0, 0, 0);
            }
        }

        // ---- epilogue: exp2, diagonal/label masking, per-row accumulate ----
        const int cbase = cbase0 + it * 128;
        #pragma unroll
        for (int tr = 0; tr < 2; ++tr) {
            const int rtile = rw + tr * 16;
            #pragma unroll
            for (int tc = 0; tc < 8; ++tc) {
                const bool diag_tile = (rtile == cbase + tc * 16);  // wave-uniform
                const int lc = collab[tc];
                #pragma unroll
                for (int reg = 0; reg < 4; ++reg) {
                    float v = EXP2(acc[tr][tc][reg]);
                    if (diag_tile && (q * 4 + reg) == c) v = 0.f;  // r == c
                    tot_a[tr][reg] += v;
                    if (rowlab[tr][reg] == lc) pos_a[tr][reg] += v;
                }
            }
        }

        __builtin_amdgcn_sched_barrier(0);
        __builtin_amdgcn_s_barrier();            // all waves done reading ldsB
        __builtin_amdgcn_sched_barrier(0);       // keep ds_writes below

        if (it < 7) {
            convert_write(r, dst);               // tile it+1 (vmcnt auto-waited)
            if (it < 6) issue_tile(emb4, cbase0 + (it + 2) * 128, trow, tc8, r);
            asm volatile("s_waitcnt lgkmcnt(0)" ::: "memory");
            __builtin_amdgcn_s_barrier();        // tile it+1 visible
            __builtin_amdgcn_sched_barrier(0);   // keep ds_reads above out
        }
    }

    // ---- reduce over the 16 column-lanes; single-writer partial slots ----
    // part[row][0..8) = tot by y-panel, part[row][8..16) = pos by y-panel.
    #pragma unroll
    for (int tr = 0; tr < 2; ++tr)
        #pragma unroll
        for (int reg = 0; reg < 4; ++reg) {
            float t = tot_a[tr][reg];
            float p = pos_a[tr][reg];
            #pragma unroll
            for (int m = 1; m < 16; m <<= 1) {
                t += __shfl_xor(t, m, 64);
                p += __shfl_xor(p, m, 64);
            }
            if (c == 0) {
                const int rrow = rw + tr * 16 + q * 4 + reg;
                __hip_atomic_store(&part[rrow * 16 + blockIdx.y], t,
                                   __ATOMIC_RELAXED, __HIP_MEMORY_SCOPE_AGENT);
                __hip_atomic_store(&part[rrow * 16 + 8 + blockIdx.y], p,
                                   __ATOMIC_RELAXED, __HIP_MEMORY_SCOPE_AGENT);
            }
        }

    // producer pattern: stores committed -> flag (relaxed agent, poison-safe MAGIC)
    asm volatile("s_waitcnt vmcnt(0)" ::: "memory");
    __syncthreads();
    if (tid == 0)
        __hip_atomic_store(&flags[bid], FLAG_MAGIC, __ATOMIC_RELAXED,
                           __HIP_MEMORY_SCOPE_AGENT);
    if (bid != 0) return;   // everyone but block 0 exits: no residency assumption

    // ---- block-0 finalize: wait all 512 flags, reduce partials, write loss ----
    while (__hip_atomic_load(&flags[tid], __ATOMIC_RELAXED,
                             __HIP_MEMORY_SCOPE_AGENT) != FLAG_MAGIC) {}
    while (__hip_atomic_load(&flags[tid + 256], __ATOMIC_RELAXED,
                             __HIP_MEMORY_SCOPE_AGENT) != FLAG_MAGIC) {}
    __syncthreads();

    float lsum = 0.f, lcnt = 0.f;
    for (int rrow = tid; rrow < N; rrow += 256) {
        float ts = 0.f, ps = 0.f;
        #pragma unroll
        for (int y = 0; y < NBY; ++y) {
            ts += __hip_atomic_load(&part[rrow * 16 + y], __ATOMIC_RELAXED,
                                    __HIP_MEMORY_SCOPE_AGENT);
            ps += __hip_atomic_load(&part[rrow * 16 + 8 + y], __ATOMIC_RELAXED,
                                    __HIP_MEMORY_SCOPE_AGENT);
        }
        const float loss = -__logf(ps / (ts + 1e-8f) + 1e-8f);
        if (ps > 0.f) { lsum += loss; lcnt += 1.f; }   // valid <=> pos>0
    }
    #pragma unroll
    for (int m = 1; m < 64; m <<= 1) {
        lsum += __shfl_xor(lsum, m, 64);
        lcnt += __shfl_xor(lcnt, m, 64);
    }
    if (lane == 0) { sred[0][wave] = lsum; sred[1][wave] = lcnt; }
    __syncthreads();
    if (tid == 0) {
        const float s = sred[0][0] + sred[0][1] + sred[0][2] + sred[0][3];
        const float n = sred[1][0] + sred[1][1] + sred[1][2] + sred[1][3];
        out[0] = (n > 0.f) ? s / fmaxf(n, 1.f) : 0.f;
    }
}

extern "C" void kernel_launch(void* const* d_in, const int* in_sizes, int n_in,
                              void* d_out, int out_size, void* d_ws, size_t ws_size,
                              hipStream_t stream) {
    const float* emb  = (const float*)d_in[0];
    const int* labels = (const int*)d_in[1];
    float* part = (float*)d_ws;                                   // 512 KB
    unsigned int* flags = (unsigned int*)(part + (size_t)N * 16); // 2 KB

    cl_fused<<<dim3(NBX, NBY), 256, 0, stream>>>(emb, labels, part, flags,
                                                 (float*)d_out);
}

// Round 3
// 130.324 us; speedup vs baseline: 1.1555x; 1.1555x over previous
//
#include <hip/hip_runtime.h>

#define N 8192
#define D 128
// (1/0.07) * log2(e): fold temperature AND base-2 conversion into A-side scale
#define SCALE_A 20.6098592f
#define NBX 64
#define NBY 16
#define NBLK (NBX * NBY)
#define ITERS 4           // 512 cols per block / 128 per tile

using short8  = __attribute__((ext_vector_type(8))) short;
using float4v = __attribute__((ext_vector_type(4))) float;

#if __has_builtin(__builtin_amdgcn_exp2f)
#define EXP2(x) __builtin_amdgcn_exp2f(x)
#else
#define EXP2(x) __expf((x) * 0.69314718f)
#endif

// float -> bf16 (RNE) as raw ushort
static __device__ inline unsigned int f2bf(float f) {
    union { float f; unsigned int u; } x;
    x.f = f;
    unsigned int u = x.u;
    return (u + 0x7FFFu + ((u >> 16) & 1u)) >> 16;
}

// Pre-pass: emb fp32 -> bf16 (unscaled, B-side) and bf16*SCALE_A (A-side).
// Also zeroes tot/pos and the ticket. 65536 threads x 16 elements.
__global__ __launch_bounds__(256) void cl_prep(
    const float* __restrict__ emb, unsigned short* __restrict__ bfB,
    unsigned short* __restrict__ bfA, float* __restrict__ tot,
    int* __restrict__ ticket)
{
    const int t = blockIdx.x * 256 + threadIdx.x;
    const float* p = emb + (size_t)t * 16;
    uint4 ob[2], oa[2];
    #pragma unroll
    for (int h = 0; h < 2; ++h) {
        float4v f0 = *(const float4v*)(p + h * 8);
        float4v f1 = *(const float4v*)(p + h * 8 + 4);
        ob[h].x = f2bf(f0[0]) | (f2bf(f0[1]) << 16);
        ob[h].y = f2bf(f0[2]) | (f2bf(f0[3]) << 16);
        ob[h].z = f2bf(f1[0]) | (f2bf(f1[1]) << 16);
        ob[h].w = f2bf(f1[2]) | (f2bf(f1[3]) << 16);
        oa[h].x = f2bf(f0[0] * SCALE_A) | (f2bf(f0[1] * SCALE_A) << 16);
        oa[h].y = f2bf(f0[2] * SCALE_A) | (f2bf(f0[3] * SCALE_A) << 16);
        oa[h].z = f2bf(f1[0] * SCALE_A) | (f2bf(f1[1] * SCALE_A) << 16);
        oa[h].w = f2bf(f1[2] * SCALE_A) | (f2bf(f1[3] * SCALE_A) << 16);
    }
    ((uint4*)bfB)[t * 2]     = ob[0];
    ((uint4*)bfB)[t * 2 + 1] = ob[1];
    ((uint4*)bfA)[t * 2]     = oa[0];
    ((uint4*)bfA)[t * 2 + 1] = oa[1];
    if (t < 2 * N) tot[t] = 0.f;    // tot and pos are contiguous
    if (t == 0) *ticket = 0;
}

// DMA-stage one 128x128 bf16 tile: global_load_lds width=16, LINEAR lds dest,
// PRE-SWIZZLED global source (chunk ^ (row&15) is an involution -> LDS image
// identical to a swizzled ds_write path; read side unchanged & conflict-free).
static __device__ __forceinline__ void stage_tile(
    const uint4* __restrict__ bfB4, int cbase, uint4* lds_dst, int tid)
{
    const uint4* src = bfB4 + (size_t)cbase * 16;
    #pragma unroll
    for (int i = 0; i < 8; ++i) {
        const int g     = tid + i * 256;
        const int row   = g >> 4;
        const int chunk = g & 15;
        __builtin_amdgcn_global_load_lds(
            (const __attribute__((address_space(1))) void*)(src + row * 16 + (chunk ^ (row & 15))),
            (__attribute__((address_space(3))) void*)(lds_dst + g),
            16, 0, 0);
    }
}

// Each block: 128 rows x 512 cols (4 tiles). Grid (64,16) = 1024 blocks =
// exactly 4/CU (launch_bounds(256,4), LDS ~35KB, regs <=128 via 2-pass acc
// split). 16 waves/CU doubles the latency hiding R2 measured as the stall
// cause (main phase 38us at 25% occupancy, all pipes <52%). Single-buffer
// LDS: [compute -> barrier -> DMA -> vmcnt(0) -> barrier]; exposed DMA
// latency is hidden by the 3 other resident blocks per CU (m114).
// Reduction = proven-fast path: HW atomicAdd per row + ticket + coalesced
// 64KB finalize (R2's part[]/flag scheme cost a 72us single-block tail).
__global__ __launch_bounds__(256, 4) void cl_main(
    const unsigned short* __restrict__ bfA, const unsigned short* __restrict__ bfB,
    const int* __restrict__ labels,
    float* __restrict__ tot, float* __restrict__ pos,
    int* __restrict__ ticket, float* __restrict__ out)
{
    __shared__ uint4 ldsB[128 * 16];   // 32KB, single buffer
    __shared__ int   s_collab[512];
    __shared__ float sred[2][4];
    __shared__ int   s_ticket;

    const int tid  = threadIdx.x;
    const int lane = tid & 63;
    const int wave = tid >> 6;
    const int q    = lane >> 4;   // quad id 0..3
    const int c    = lane & 15;
    const int rw     = blockIdx.x * 128 + wave * 32;
    const int cbase0 = blockIdx.y * 512;
    const uint4* bfB4 = (const uint4*)bfB;

    stage_tile(bfB4, cbase0, &ldsB[0], tid);     // tile 0 DMA in flight

    // ---- A fragments: 16B loads from prescaled bf16 array, once per block ----
    short8 afrag[2][4];
    int rowlab[2][4];
    #pragma unroll
    for (int tr = 0; tr < 2; ++tr) {
        const int arow = rw + tr * 16 + c;
        #pragma unroll
        for (int ks = 0; ks < 4; ++ks)
            afrag[tr][ks] = *(const short8*)(bfA + (size_t)arow * D + ks * 32 + q * 8);
        #pragma unroll
        for (int reg = 0; reg < 4; ++reg)
            rowlab[tr][reg] = labels[rw + tr * 16 + q * 4 + reg];
    }

    // ---- column labels -> LDS once (512 labels, 2 per thread) ----
    {
        int2 lv = *(const int2*)(labels + cbase0 + tid * 2);
        *(int2*)(&s_collab[tid * 2]) = lv;
    }
    asm volatile("s_waitcnt vmcnt(0) lgkmcnt(0)" ::: "memory"); // DMA + collab
    __builtin_amdgcn_s_barrier();
    __builtin_amdgcn_sched_barrier(0);

    float tot_a[2][4] = {{0.f,0.f,0.f,0.f},{0.f,0.f,0.f,0.f}};
    float pos_a[2][4] = {{0.f,0.f,0.f,0.f},{0.f,0.f,0.f,0.f}};

    #pragma unroll 1
    for (int it = 0; it < ITERS; ++it) {
        const int cbase = cbase0 + it * 128;
        int collab[8];
        #pragma unroll
        for (int tc = 0; tc < 8; ++tc) collab[tc] = s_collab[it * 128 + tc * 16 + c];

        const short8* ldsS = (const short8*)ldsB;

        // ---- two 4-column passes: acc live range = 32 VGPR (fits 128-cap) ----
        #pragma unroll
        for (int pass = 0; pass < 2; ++pass) {
            float4v acc[2][4];
            #pragma unroll
            for (int tr = 0; tr < 2; ++tr)
                #pragma unroll
                for (int tcl = 0; tcl < 4; ++tcl) {
                    float4v z = {0.f, 0.f, 0.f, 0.f};
                    acc[tr][tcl] = z;
                }

            #pragma unroll
            for (int ks = 0; ks < 4; ++ks) {
                const short8* pk = ldsS + c * 16 + ((ks * 4 + q) ^ c);
                #pragma unroll
                for (int tcl = 0; tcl < 4; ++tcl) {
                    const int tc = pass * 4 + tcl;
                    short8 b = pk[tc * 256];
                    #pragma unroll
                    for (int tr = 0; tr < 2; ++tr)
                        acc[tr][tcl] = __builtin_amdgcn_mfma_f32_16x16x32_bf16(
                            afrag[tr][ks], b, acc[tr][tcl], 0, 0, 0);
                }
            }

            // ---- epilogue: exp2, diagonal/label masking, per-row accumulate ----
            #pragma unroll
            for (int tr = 0; tr < 2; ++tr) {
                const int rtile = rw + tr * 16;
                #pragma unroll
                for (int tcl = 0; tcl < 4; ++tcl) {
                    const int tc = pass * 4 + tcl;
                    const bool diag_tile = (rtile == cbase + tc * 16); // wave-uniform
                    const int lc = collab[tc];
                    #pragma unroll
                    for (int reg = 0; reg < 4; ++reg) {
                        float v = EXP2(acc[tr][tcl][reg]);
                        if (diag_tile && (q * 4 + reg) == c) v = 0.f;  // r == c
                        tot_a[tr][reg] += v;
                        if (rowlab[tr][reg] == lc) pos_a[tr][reg] += v;
                    }
                }
            }
        }

        __builtin_amdgcn_sched_barrier(0);
        __builtin_amdgcn_s_barrier();            // all waves done reading ldsB
        __builtin_amdgcn_sched_barrier(0);       // keep next DMA below

        if (it < ITERS - 1) {
            stage_tile(bfB4, cbase0 + (it + 1) * 128, &ldsB[0], tid);
            asm volatile("s_waitcnt vmcnt(0)" ::: "memory");
            __builtin_amdgcn_s_barrier();        // next tile visible
            __builtin_amdgcn_sched_barrier(0);
        }
    }

    // ---- reduce over the 16 column-lanes, one atomic per row ----
    #pragma unroll
    for (int tr = 0; tr < 2; ++tr)
        #pragma unroll
        for (int reg = 0; reg < 4; ++reg) {
            float t = tot_a[tr][reg];
            float p = pos_a[tr][reg];
            #pragma unroll
            for (int m = 1; m < 16; m <<= 1) {
                t += __shfl_xor(t, m, 64);
                p += __shfl_xor(p, m, 64);
            }
            if (c == 0) {
                const int r = rw + tr * 16 + q * 4 + reg;
                atomicAdd(&tot[r], t);   // device-scope RMW at coherent point
                atomicAdd(&pos[r], p);
            }
        }

    // ---- last-block finalize: completion-wait + relaxed ticket (NO cache ops)
    asm volatile("s_waitcnt vmcnt(0)" ::: "memory");  // our atomics committed
    __syncthreads();
    if (tid == 0)
        s_ticket = __hip_atomic_fetch_add(ticket, 1, __ATOMIC_RELAXED,
                                          __HIP_MEMORY_SCOPE_AGENT);
    __syncthreads();
    if (s_ticket != NBLK - 1) return;

    float lsum = 0.f, lcnt = 0.f;
    #pragma unroll 4
    for (int i = tid; i < N; i += 256) {
        const float t = __hip_atomic_load(&tot[i], __ATOMIC_RELAXED,
                                          __HIP_MEMORY_SCOPE_AGENT);
        const float p = __hip_atomic_load(&pos[i], __ATOMIC_RELAXED,
                                          __HIP_MEMORY_SCOPE_AGENT);
        const float loss = -__logf(p / (t + 1e-8f) + 1e-8f);
        if (p > 0.f) { lsum += loss; lcnt += 1.f; }   // valid <=> pos>0
    }
    #pragma unroll
    for (int m = 1; m < 64; m <<= 1) {
        lsum += __shfl_xor(lsum, m, 64);
        lcnt += __shfl_xor(lcnt, m, 64);
    }
    if (lane == 0) { sred[0][wave] = lsum; sred[1][wave] = lcnt; }
    __syncthreads();
    if (tid == 0) {
        const float s = sred[0][0] + sred[0][1] + sred[0][2] + sred[0][3];
        const float n = sred[1][0] + sred[1][1] + sred[1][2] + sred[1][3];
        out[0] = (n > 0.f) ? s / fmaxf(n, 1.f) : 0.f;
    }
}

extern "C" void kernel_launch(void* const* d_in, const int* in_sizes, int n_in,
                              void* d_out, int out_size, void* d_ws, size_t ws_size,
                              hipStream_t stream) {
    const float* emb  = (const float*)d_in[0];
    const int* labels = (const int*)d_in[1];
    unsigned short* bfB = (unsigned short*)d_ws;                       // 2 MB
    unsigned short* bfA = bfB + (size_t)N * D;                         // 2 MB
    float* tot    = (float*)(bfA + (size_t)N * D);
    float* pos    = tot + N;
    int*   ticket = (int*)(pos + N);

    cl_prep<<<256, 256, 0, stream>>>(emb, bfB, bfA, tot, ticket);
    cl_main<<<dim3(NBX, NBY), 256, 0, stream>>>(bfA, bfB, labels, tot, pos,
                                                ticket, (float*)d_out);
}

// Round 4
// 93.914 us; speedup vs baseline: 1.6035x; 1.3877x over previous
//
#include <hip/hip_runtime.h>

#define N 8192
#define D 128
// (1/0.07) * log2(e): fold temperature AND base-2 conversion into A-side scale
#define SCALE_A 20.6098592f
#define NBX 128           // 8192 rows / 64 rows per block
#define NBY 8             // 8192 cols / 1024 cols per block
#define NBLK (NBX * NBY)
#define ITERS 8           // 1024 cols per block / 128 per tile

using short8  = __attribute__((ext_vector_type(8))) short;
using float4v = __attribute__((ext_vector_type(4))) float;

#if __has_builtin(__builtin_amdgcn_exp2f)
#define EXP2(x) __builtin_amdgcn_exp2f(x)
#else
#define EXP2(x) __expf((x) * 0.69314718f)
#endif

// float -> bf16 (RNE) as raw ushort
static __device__ inline unsigned int f2bf(float f) {
    union { float f; unsigned int u; } x;
    x.f = f;
    unsigned int u = x.u;
    return (u + 0x7FFFu + ((u >> 16) & 1u)) >> 16;
}

// Pre-pass: emb fp32 -> bf16 (unscaled, B-side) and bf16*SCALE_A (A-side).
// Also zeroes tot/pos and the ticket. 65536 threads x 16 elements.
__global__ __launch_bounds__(256) void cl_prep(
    const float* __restrict__ emb, unsigned short* __restrict__ bfB,
    unsigned short* __restrict__ bfA, float* __restrict__ tot,
    int* __restrict__ ticket)
{
    const int t = blockIdx.x * 256 + threadIdx.x;
    const float* p = emb + (size_t)t * 16;
    uint4 ob[2], oa[2];
    #pragma unroll
    for (int h = 0; h < 2; ++h) {
        float4v f0 = *(const float4v*)(p + h * 8);
        float4v f1 = *(const float4v*)(p + h * 8 + 4);
        ob[h].x = f2bf(f0[0]) | (f2bf(f0[1]) << 16);
        ob[h].y = f2bf(f0[2]) | (f2bf(f0[3]) << 16);
        ob[h].z = f2bf(f1[0]) | (f2bf(f1[1]) << 16);
        ob[h].w = f2bf(f1[2]) | (f2bf(f1[3]) << 16);
        oa[h].x = f2bf(f0[0] * SCALE_A) | (f2bf(f0[1] * SCALE_A) << 16);
        oa[h].y = f2bf(f0[2] * SCALE_A) | (f2bf(f0[3] * SCALE_A) << 16);
        oa[h].z = f2bf(f1[0] * SCALE_A) | (f2bf(f1[1] * SCALE_A) << 16);
        oa[h].w = f2bf(f1[2] * SCALE_A) | (f2bf(f1[3] * SCALE_A) << 16);
    }
    ((uint4*)bfB)[t * 2]     = ob[0];
    ((uint4*)bfB)[t * 2 + 1] = ob[1];
    ((uint4*)bfA)[t * 2]     = oa[0];
    ((uint4*)bfA)[t * 2 + 1] = oa[1];
    if (t < 2 * N) tot[t] = 0.f;    // tot and pos are contiguous
    if (t == 0) *ticket = 0;
}

// DMA-stage one 128x128 bf16 tile: global_load_lds width=16, LINEAR lds dest,
// PRE-SWIZZLED global source (chunk ^ (row&15) is an involution -> LDS image
// identical to a swizzled ds_write path; read side unchanged & conflict-free).
static __device__ __forceinline__ void stage_tile(
    const uint4* __restrict__ bfB4, int cbase, uint4* lds_dst, int tid)
{
    const uint4* src = bfB4 + (size_t)cbase * 16;
    #pragma unroll
    for (int i = 0; i < 8; ++i) {
        const int g     = tid + i * 256;
        const int row   = g >> 4;
        const int chunk = g & 15;
        __builtin_amdgcn_global_load_lds(
            (const __attribute__((address_space(1))) void*)(src + row * 16 + (chunk ^ (row & 15))),
            (__attribute__((address_space(3))) void*)(lds_dst + g),
            16, 0, 0);
    }
}

// Each block: 64 rows x 1024 cols; per-wave output = 16 rows x 128 cols.
// Halved wave tile => register floor ~100 unified (afrag 16 + acc 32 +
// tot/pos 8 + misc), genuinely under the 128-reg cap of
// __launch_bounds__(256,4) — unlike R3's 190-into-128 spill. 4 blocks/CU
// (LDS 36.9KB x 4 = 148KB, regs <=128) => 16 waves/CU = 2x R0's latency
// hiding. LDS read traffic doubles but was at ~16% of budget. Reduction =
// proven-fast path: HW atomicAdd per row + ticket + coalesced finalize.
__global__ __launch_bounds__(256, 4) void cl_main(
    const unsigned short* __restrict__ bfA, const unsigned short* __restrict__ bfB,
    const int* __restrict__ labels,
    float* __restrict__ tot, float* __restrict__ pos,
    int* __restrict__ ticket, float* __restrict__ out)
{
    __shared__ uint4 ldsB[128 * 16];   // 32KB, single buffer
    __shared__ int   s_collab[1024];
    __shared__ float sred[2][4];
    __shared__ int   s_ticket;

    const int tid  = threadIdx.x;
    const int lane = tid & 63;
    const int wave = tid >> 6;
    const int q    = lane >> 4;   // quad id 0..3
    const int c    = lane & 15;
    const int rw     = blockIdx.x * 64 + wave * 16;   // this wave's 16 rows
    const int cbase0 = blockIdx.y * 1024;
    const uint4* bfB4 = (const uint4*)bfB;

    stage_tile(bfB4, cbase0, &ldsB[0], tid);     // tile 0 DMA in flight

    // ---- A fragments: 16B loads from prescaled bf16 array, once per block ----
    short8 afrag[4];
    int rowlab[4];
    {
        const int arow = rw + c;
        #pragma unroll
        for (int ks = 0; ks < 4; ++ks)
            afrag[ks] = *(const short8*)(bfA + (size_t)arow * D + ks * 32 + q * 8);
        #pragma unroll
        for (int reg = 0; reg < 4; ++reg)
            rowlab[reg] = labels[rw + q * 4 + reg];
    }

    // ---- column labels -> LDS once (1024 labels, 4 per thread) ----
    {
        int4 lv = *(const int4*)(labels + cbase0 + tid * 4);
        *(int4*)(&s_collab[tid * 4]) = lv;
    }
    asm volatile("s_waitcnt vmcnt(0) lgkmcnt(0)" ::: "memory"); // DMA + collab
    __builtin_amdgcn_s_barrier();
    __builtin_amdgcn_sched_barrier(0);

    float tot_a[4] = {0.f, 0.f, 0.f, 0.f};
    float pos_a[4] = {0.f, 0.f, 0.f, 0.f};

    #pragma unroll 1
    for (int it = 0; it < ITERS; ++it) {
        const int cbase = cbase0 + it * 128;

        // ---- MFMA: 1 tile-row x 8 tile-cols, K=128 in 4 steps ----
        float4v acc[8];
        #pragma unroll
        for (int tc = 0; tc < 8; ++tc) {
            float4v z = {0.f, 0.f, 0.f, 0.f};
            acc[tc] = z;
        }

        const short8* ldsS = (const short8*)ldsB;
        #pragma unroll
        for (int ks = 0; ks < 4; ++ks) {
            const short8* pk = ldsS + c * 16 + ((ks * 4 + q) ^ c);
            #pragma unroll
            for (int tc = 0; tc < 8; ++tc) {
                short8 b = pk[tc * 256];
                acc[tc] = __builtin_amdgcn_mfma_f32_16x16x32_bf16(
                    afrag[ks], b, acc[tc], 0, 0, 0);
            }
        }

        // ---- epilogue: exp2, diagonal/label masking, per-row accumulate ----
        #pragma unroll
        for (int tc = 0; tc < 8; ++tc) {
            const bool diag_tile = (rw == cbase + tc * 16);   // wave-uniform
            const int lc = s_collab[it * 128 + tc * 16 + c];  // lazy: saves VGPRs
            #pragma unroll
            for (int reg = 0; reg < 4; ++reg) {
                float v = EXP2(acc[tc][reg]);
                if (diag_tile && (q * 4 + reg) == c) v = 0.f;  // r == c
                tot_a[reg] += v;
                if (rowlab[reg] == lc) pos_a[reg] += v;
            }
        }

        __builtin_amdgcn_sched_barrier(0);
        __builtin_amdgcn_s_barrier();            // all waves done reading ldsB
        __builtin_amdgcn_sched_barrier(0);       // keep next DMA below

        if (it < ITERS - 1) {
            stage_tile(bfB4, cbase0 + (it + 1) * 128, &ldsB[0], tid);
            asm volatile("s_waitcnt vmcnt(0)" ::: "memory");
            __builtin_amdgcn_s_barrier();        // next tile visible
            __builtin_amdgcn_sched_barrier(0);
        }
    }

    // ---- reduce over the 16 column-lanes, one atomic per row ----
    #pragma unroll
    for (int reg = 0; reg < 4; ++reg) {
        float t = tot_a[reg];
        float p = pos_a[reg];
        #pragma unroll
        for (int m = 1; m < 16; m <<= 1) {
            t += __shfl_xor(t, m, 64);
            p += __shfl_xor(p, m, 64);
        }
        if (c == 0) {
            const int r = rw + q * 4 + reg;
            atomicAdd(&tot[r], t);   // device-scope RMW at coherent point
            atomicAdd(&pos[r], p);
        }
    }

    // ---- last-block finalize: completion-wait + relaxed ticket (NO cache ops)
    asm volatile("s_waitcnt vmcnt(0)" ::: "memory");  // our atomics committed
    __syncthreads();
    if (tid == 0)
        s_ticket = __hip_atomic_fetch_add(ticket, 1, __ATOMIC_RELAXED,
                                          __HIP_MEMORY_SCOPE_AGENT);
    __syncthreads();
    if (s_ticket != NBLK - 1) return;

    float lsum = 0.f, lcnt = 0.f;
    #pragma unroll 4
    for (int i = tid; i < N; i += 256) {
        const float t = __hip_atomic_load(&tot[i], __ATOMIC_RELAXED,
                                          __HIP_MEMORY_SCOPE_AGENT);
        const float p = __hip_atomic_load(&pos[i], __ATOMIC_RELAXED,
                                          __HIP_MEMORY_SCOPE_AGENT);
        const float loss = -__logf(p / (t + 1e-8f) + 1e-8f);
        if (p > 0.f) { lsum += loss; lcnt += 1.f; }   // valid <=> pos>0
    }
    #pragma unroll
    for (int m = 1; m < 64; m <<= 1) {
        lsum += __shfl_xor(lsum, m, 64);
        lcnt += __shfl_xor(lcnt, m, 64);
    }
    if (lane == 0) { sred[0][wave] = lsum; sred[1][wave] = lcnt; }
    __syncthreads();
    if (tid == 0) {
        const float s = sred[0][0] + sred[0][1] + sred[0][2] + sred[0][3];
        const float n = sred[1][0] + sred[1][1] + sred[1][2] + sred[1][3];
        out[0] = (n > 0.f) ? s / fmaxf(n, 1.f) : 0.f;
    }
}

extern "C" void kernel_launch(void* const* d_in, const int* in_sizes, int n_in,
                              void* d_out, int out_size, void* d_ws, size_t ws_size,
                              hipStream_t stream) {
    const float* emb  = (const float*)d_in[0];
    const int* labels = (const int*)d_in[1];
    unsigned short* bfB = (unsigned short*)d_ws;                       // 2 MB
    unsigned short* bfA = bfB + (size_t)N * D;                         // 2 MB
    float* tot    = (float*)(bfA + (size_t)N * D);
    float* pos    = tot + N;
    int*   ticket = (int*)(pos + N);

    cl_prep<<<256, 256, 0, stream>>>(emb, bfB, bfA, tot, ticket);
    cl_main<<<dim3(NBX, NBY), 256, 0, stream>>>(bfA, bfB, labels, tot, pos,
                                                ticket, (float*)d_out);
}